// Round 9
// baseline (123.878 us; speedup 1.0000x reference)
//
#include <hip/hip_runtime.h>

#define NB 32
#define NN 256
#define DD 64
#define GG 4            // node-groups per batch
#define NPB 64          // nodes per block (conv kernels)

// R9: same 3-kernel stream pipeline as R8 (stream boundaries beat coop
// grid.sync — R7), but conv kernels at 1024 thr (16 waves -> 4 waves/SIMD,
// 2x the latency hiding for the s_load/ds_read chain; wave = 4-dim slice,
// still wave-uniform -> scalar weight loads) and poolhead rebuilt with no
// LDS staging (epilogue -> shfl butterfly directly; 67KB TT eliminated).
// Fixed harness cost ~78us (256MiB 0xAA fill + input restores) is not
// addressable from kernel code.
//
// ws layout (floats):
//   TI    @ 0        NB*NN*DD = 524288
//   PMAX1 @ 524288   NB*GG*DD = 8192
//   PMIN1 @ 532480   8192
//   PMAX2 @ 540672   8192
//   PMIN2 @ 548864   8192      (total 557056 floats = 2.23 MB)

__global__ __launch_bounds__(1024) void k_conv1(
    const float* __restrict__ x,
    const float* __restrict__ W1,  const float* __restrict__ b1,
    const float* __restrict__ g1,  const float* __restrict__ beta1,
    const float* __restrict__ We1,
    float* __restrict__ TI, float* __restrict__ PMAX, float* __restrict__ PMIN)
{
    __shared__ float Hs[NPB * 65];   // stride 65 -> 2-way bank alias only (free)
    const int b  = blockIdx.x >> 2;
    const int g  = blockIdx.x & 3;
    const int l  = threadIdx.x & 63;                                 // node lane
    const int w  = __builtin_amdgcn_readfirstlane(threadIdx.x >> 6); // wave 0..15
    const int n  = g * NPB + l;
    const int d0 = w * 4;                                            // 4-dim slice

    // ---- layer 1: h[n, d0..d0+4) ----
    {
        float4 xv = *(const float4*)(x + ((size_t)b * NN + n) * 4);
        float a[4];
#pragma unroll
        for (int j = 0; j < 4; ++j) a[j] = b1[d0 + j];
#pragma unroll
        for (int j = 0; j < 4; ++j) a[j] = fmaf(xv.x, W1[0 * DD + d0 + j], a[j]);
#pragma unroll
        for (int j = 0; j < 4; ++j) a[j] = fmaf(xv.y, W1[1 * DD + d0 + j], a[j]);
#pragma unroll
        for (int j = 0; j < 4; ++j) a[j] = fmaf(xv.z, W1[2 * DD + d0 + j], a[j]);
#pragma unroll
        for (int j = 0; j < 4; ++j) a[j] = fmaf(xv.w, W1[3 * DD + d0 + j], a[j]);
#pragma unroll
        for (int j = 0; j < 4; ++j)
            Hs[l * 65 + d0 + j] = g1[d0 + j] * fmaxf(a[j], 0.f) + beta1[d0 + j];
    }
    __syncthreads();

    // ---- conv1 matvec: 4 dims x 64 k; weights s_load (wave-uniform) ----
    float ti[4] = {0.f, 0.f, 0.f, 0.f}, tj[4] = {0.f, 0.f, 0.f, 0.f};
#pragma unroll
    for (int k = 0; k < DD; ++k) {
        const float hk = Hs[l * 65 + k];
        const float* wi = We1 + k * DD + d0;
        const float* wj = We1 + (DD + k) * DD + d0;
#pragma unroll
        for (int j = 0; j < 4; ++j) {
            ti[j] = fmaf(hk, wi[j], ti[j]);
            tj[j] = fmaf(hk, wj[j], tj[j]);
        }
    }
    *(float4*)(TI + ((size_t)(b * NN + n)) * DD + d0) =
        make_float4(ti[0], ti[1], ti[2], ti[3]);

    // butterfly max/min of tj over 64 nodes (lanes)
    float mx[4], mn[4];
#pragma unroll
    for (int j = 0; j < 4; ++j) { mx[j] = tj[j]; mn[j] = tj[j]; }
#pragma unroll
    for (int m = 1; m < 64; m <<= 1) {
#pragma unroll
        for (int j = 0; j < 4; ++j) {
            mx[j] = fmaxf(mx[j], __shfl_xor(mx[j], m, 64));
            mn[j] = fminf(mn[j], __shfl_xor(mn[j], m, 64));
        }
    }
    float smx = mx[0], smn = mn[0];
#pragma unroll
    for (int j = 1; j < 4; ++j) {
        smx = (l == j) ? mx[j] : smx;
        smn = (l == j) ? mn[j] : smn;
    }
    if (l < 4) {
        PMAX[(b * GG + g) * DD + d0 + l] = smx;
        PMIN[(b * GG + g) * DD + d0 + l] = smn;
    }
}

__global__ __launch_bounds__(1024) void k_conv2(
    const float* __restrict__ PMAXin, const float* __restrict__ PMINin,
    const float* __restrict__ beP, const float* __restrict__ geP,
    const float* __restrict__ bteP,
    const float* __restrict__ We,
    float* __restrict__ TI, float* __restrict__ PMAX, float* __restrict__ PMIN)
{
    __shared__ float Hs[NPB * 65];
    const int b  = blockIdx.x >> 2;
    const int g  = blockIdx.x & 3;
    const int l  = threadIdx.x & 63;
    const int w  = __builtin_amdgcn_readfirstlane(threadIdx.x >> 6);
    const int n  = g * NPB + l;
    const int d0 = w * 4;

    // epilogue1: h = ge*relu(ti1 + pick(tj1 reduced) + be) + bte
    {
        float4 tv = *(const float4*)(TI + ((size_t)(b * NN + n)) * DD + d0);
        float tiv[4] = {tv.x, tv.y, tv.z, tv.w};
#pragma unroll
        for (int j = 0; j < 4; ++j) {
            float rmax = fmaxf(fmaxf(PMAXin[(b * GG + 0) * DD + d0 + j],
                                     PMAXin[(b * GG + 1) * DD + d0 + j]),
                               fmaxf(PMAXin[(b * GG + 2) * DD + d0 + j],
                                     PMAXin[(b * GG + 3) * DD + d0 + j]));
            float rmin = fminf(fminf(PMINin[(b * GG + 0) * DD + d0 + j],
                                     PMINin[(b * GG + 1) * DD + d0 + j]),
                               fminf(PMINin[(b * GG + 2) * DD + d0 + j],
                                     PMINin[(b * GG + 3) * DD + d0 + j]));
            float gv = geP[d0 + j];
            float sv = tiv[j] + (gv >= 0.f ? rmax : rmin) + beP[d0 + j];
            Hs[l * 65 + d0 + j] = gv * fmaxf(sv, 0.f) + bteP[d0 + j];
        }
    }
    __syncthreads();

    float ti[4] = {0.f, 0.f, 0.f, 0.f}, tj[4] = {0.f, 0.f, 0.f, 0.f};
#pragma unroll
    for (int k = 0; k < DD; ++k) {
        const float hk = Hs[l * 65 + k];
        const float* wi = We + k * DD + d0;
        const float* wj = We + (DD + k) * DD + d0;
#pragma unroll
        for (int j = 0; j < 4; ++j) {
            ti[j] = fmaf(hk, wi[j], ti[j]);
            tj[j] = fmaf(hk, wj[j], tj[j]);
        }
    }
    *(float4*)(TI + ((size_t)(b * NN + n)) * DD + d0) =   // in-place: same thread read it
        make_float4(ti[0], ti[1], ti[2], ti[3]);

    float mx[4], mn[4];
#pragma unroll
    for (int j = 0; j < 4; ++j) { mx[j] = tj[j]; mn[j] = tj[j]; }
#pragma unroll
    for (int m = 1; m < 64; m <<= 1) {
#pragma unroll
        for (int j = 0; j < 4; ++j) {
            mx[j] = fmaxf(mx[j], __shfl_xor(mx[j], m, 64));
            mn[j] = fminf(mn[j], __shfl_xor(mn[j], m, 64));
        }
    }
    float smx = mx[0], smn = mn[0];
#pragma unroll
    for (int j = 1; j < 4; ++j) {
        smx = (l == j) ? mx[j] : smx;
        smn = (l == j) ? mn[j] : smn;
    }
    if (l < 4) {
        PMAX[(b * GG + g) * DD + d0 + l] = smx;
        PMIN[(b * GG + g) * DD + d0 + l] = smn;
    }
}

// conv2 epilogue + pooling + head, 32 blocks x 1024 threads, NO LDS staging:
// wave w: node group g3 = w&3 (64 nodes in lanes), dims d0 = (w>>2)*16.
// Epilogue value feeds the sum/max butterfly directly.
__global__ __launch_bounds__(1024) void k_poolhead(
    const float* __restrict__ PMAXin, const float* __restrict__ PMINin,
    const float* __restrict__ beP, const float* __restrict__ geP,
    const float* __restrict__ bteP,
    const float* __restrict__ TI,
    const float* __restrict__ Wg1, const float* __restrict__ bg1,
    const float* __restrict__ Wg2, const float* __restrict__ bg2,
    float* __restrict__ out)
{
    __shared__ float PS[GG * DD];     // pooling partial sums  [group][dim]
    __shared__ float PX[GG * DD];     // pooling partial maxes [group][dim]
    __shared__ float XG[2 * DD];
    __shared__ float HID[DD];

    const int b  = blockIdx.x;
    const int t  = threadIdx.x;
    const int l  = t & 63;
    const int w  = __builtin_amdgcn_readfirstlane(t >> 6);   // wave 0..15
    const int g3 = w & 3;                                    // node group
    const int d0 = (w >> 2) * 16;                            // 16-dim slice
    const int n  = g3 * 64 + l;

    // epilogue2 -> hv[16], rmax/rmin inline (wave-uniform s_loads)
    float sm[16], mx[16];
    {
        const float* tip = TI + ((size_t)(b * NN + n)) * DD + d0;
#pragma unroll
        for (int j4 = 0; j4 < 4; ++j4) {
            float4 tv = ((const float4*)tip)[j4];
            float tvv[4] = {tv.x, tv.y, tv.z, tv.w};
#pragma unroll
            for (int q = 0; q < 4; ++q) {
                const int j = 4 * j4 + q;
                float rmax = fmaxf(fmaxf(PMAXin[(b * GG + 0) * DD + d0 + j],
                                         PMAXin[(b * GG + 1) * DD + d0 + j]),
                                   fmaxf(PMAXin[(b * GG + 2) * DD + d0 + j],
                                         PMAXin[(b * GG + 3) * DD + d0 + j]));
                float rmin = fminf(fminf(PMINin[(b * GG + 0) * DD + d0 + j],
                                         PMINin[(b * GG + 1) * DD + d0 + j]),
                                   fminf(PMINin[(b * GG + 2) * DD + d0 + j],
                                         PMINin[(b * GG + 3) * DD + d0 + j]));
                float gv = geP[d0 + j];
                float sv = tvv[q] + (gv >= 0.f ? rmax : rmin) + beP[d0 + j];
                float hv = gv * fmaxf(sv, 0.f) + bteP[d0 + j];
                sm[j] = hv;
                mx[j] = hv;
            }
        }
    }
    // butterfly sum/max over the 64 nodes in this wave
#pragma unroll
    for (int m = 1; m < 64; m <<= 1) {
#pragma unroll
        for (int j = 0; j < 16; ++j) {
            sm[j] += __shfl_xor(sm[j], m, 64);
            mx[j] = fmaxf(mx[j], __shfl_xor(mx[j], m, 64));
        }
    }
    float ssm = sm[0], smx = mx[0];
#pragma unroll
    for (int j = 1; j < 16; ++j) {
        ssm = (l == j) ? sm[j] : ssm;
        smx = (l == j) ? mx[j] : smx;
    }
    if (l < 16) {
        PS[g3 * DD + d0 + l] = ssm;
        PX[g3 * DD + d0 + l] = smx;
    }
    __syncthreads();

    if (t < 64) {
        float asum = PS[0 * DD + t] + PS[1 * DD + t] + PS[2 * DD + t] + PS[3 * DD + t];
        float amax = fmaxf(fmaxf(PX[0 * DD + t], PX[1 * DD + t]),
                           fmaxf(PX[2 * DD + t], PX[3 * DD + t]));
        XG[t]      = asum * (1.f / 256.f);
        XG[64 + t] = amax;
    }
    __syncthreads();

    if (t < 64) {
        float a = bg1[t];
#pragma unroll
        for (int k = 0; k < 2 * DD; ++k) a = fmaf(XG[k], Wg1[k * DD + t], a);
        HID[t] = fmaxf(a, 0.f);
    }
    __syncthreads();
    if (t < 2) {
        float o = bg2[t];
#pragma unroll
        for (int j = 0; j < DD; ++j) o = fmaf(HID[j], Wg2[j * 2 + t], o);
        out[b * 2 + t] = o;
    }
}

extern "C" void kernel_launch(void* const* d_in, const int* in_sizes, int n_in,
                              void* d_out, int out_size, void* d_ws, size_t ws_size,
                              hipStream_t stream) {
    const float* x     = (const float*)d_in[0];
    const float* W1    = (const float*)d_in[1];
    const float* b1    = (const float*)d_in[2];
    const float* g1    = (const float*)d_in[3];
    const float* beta1 = (const float*)d_in[4];
    const float* We1   = (const float*)d_in[5];
    const float* be1   = (const float*)d_in[6];
    const float* ge1   = (const float*)d_in[7];
    const float* bte1  = (const float*)d_in[8];
    const float* We2   = (const float*)d_in[9];
    const float* be2   = (const float*)d_in[10];
    const float* ge2   = (const float*)d_in[11];
    const float* bte2  = (const float*)d_in[12];
    const float* Wg1   = (const float*)d_in[13];
    const float* bg1   = (const float*)d_in[14];
    const float* Wg2   = (const float*)d_in[15];
    const float* bg2   = (const float*)d_in[16];

    float* ws    = (float*)d_ws;
    float* TI    = ws;
    float* PMAX1 = ws + 524288;
    float* PMIN1 = ws + 532480;
    float* PMAX2 = ws + 540672;
    float* PMIN2 = ws + 548864;

    k_conv1<<<dim3(NB * GG), dim3(1024), 0, stream>>>(
        x, W1, b1, g1, beta1, We1, TI, PMAX1, PMIN1);
    k_conv2<<<dim3(NB * GG), dim3(1024), 0, stream>>>(
        PMAX1, PMIN1, be1, ge1, bte1, We2, TI, PMAX2, PMIN2);
    k_poolhead<<<dim3(NB), dim3(1024), 0, stream>>>(
        PMAX2, PMIN2, be2, ge2, bte2, TI, Wg1, bg1, Wg2, bg2, (float*)d_out);
}